// Round 12
// baseline (164.149 us; speedup 1.0000x reference)
//
#include <hip/hip_runtime.h>
#include <math.h>

typedef short  short8  __attribute__((ext_vector_type(8)));
typedef short  short4v __attribute__((ext_vector_type(4)));
typedef float  f32x4   __attribute__((ext_vector_type(4)));

constexpr int D   = 1024;   // d_in = d_g
constexpr int K   = 512;    // codebook size
constexpr int BM  = 64;     // rows per block (vq_topk)
constexpr int KP  = 256;    // k-panel (f32 elements)
constexpr int ROWS = 16384;
constexpr float GAP_T = 2e-3f;   // ~25 sigma of 3-term split-bf16 noise

__device__ __forceinline__ unsigned short f2bf(float f) {
    unsigned u = __float_as_uint(f);
    u += 0x7FFFu + ((u >> 16) & 1u);          // round-to-nearest-even
    return (unsigned short)(u >> 16);
}
__device__ __forceinline__ float bf2f(unsigned short h) {
    return __uint_as_float(((unsigned)h) << 16);
}
// convert one float4 -> bf16 hi/lo 8B chunks and store to LDS
__device__ __forceinline__ void cvt_write(const float4 v,
                                          unsigned char* dh, unsigned char* dl) {
    const unsigned short h0 = f2bf(v.x), h1 = f2bf(v.y), h2 = f2bf(v.z), h3 = f2bf(v.w);
    const short4v hv = { (short)h0, (short)h1, (short)h2, (short)h3 };
    const short4v lv = { (short)f2bf(v.x - bf2f(h0)), (short)f2bf(v.y - bf2f(h1)),
                         (short)f2bf(v.z - bf2f(h2)), (short)f2bf(v.w - bf2f(h3)) };
    *reinterpret_cast<short4v*>(dh) = hv;
    *reinterpret_cast<short4v*>(dl) = lv;
}

// ---------------------------------------------------------------------------
// Kernel A: normalize codebook rows; emit MFMA-fragment-packed bf16 hi/lo
// (cbp) + f32 copy (cff, for rescue). Also zeroes the rescue counter.
// ---------------------------------------------------------------------------
__global__ __launch_bounds__(256)
void prep_codebook(const float* __restrict__ cb, unsigned short* __restrict__ cbp,
                   float* __restrict__ cff, int* __restrict__ rcnt) {
    if (blockIdx.x == 0 && threadIdx.x == 0) rcnt[0] = 0;
    const int n = blockIdx.x, tid = threadIdx.x;
    const float4 v = reinterpret_cast<const float4*>(cb + (size_t)n * D)[tid];
    float ss = v.x*v.x + v.y*v.y + v.z*v.z + v.w*v.w;
#pragma unroll
    for (int off = 32; off > 0; off >>= 1) ss += __shfl_down(ss, off);
    __shared__ float wss[4];
    if ((tid & 63) == 0) wss[tid >> 6] = ss;
    __syncthreads();
    const float tot   = wss[0] + wss[1] + wss[2] + wss[3];
    const float scale = 1.0f / fmaxf(sqrtf(tot), 1e-12f);
    float f[4] = { v.x*scale, v.y*scale, v.z*scale, v.w*scale };
    float4 fv = { f[0], f[1], f[2], f[3] };
    reinterpret_cast<float4*>(cff + (size_t)n * D)[tid] = fv;

    unsigned short h[4], lo[4];
#pragma unroll
    for (int i = 0; i < 4; ++i) { h[i] = f2bf(f[i]); lo[i] = f2bf(f[i] - bf2f(h[i])); }
    short4v hv = { (short)h[0], (short)h[1], (short)h[2], (short)h[3] };
    short4v lv = { (short)lo[0], (short)lo[1], (short)lo[2], (short)lo[3] };

    const int nt_g = n >> 4;           // code tile 0..31
    const int lr   = n & 15;
    const int ks_g = tid >> 3;         // k-step 0..31
    const int lg   = (tid >> 1) & 3;
    const int half = tid & 1;
    const size_t fbase = ((size_t)(nt_g * 32 + ks_g) * 2) * 1024;   // bytes
    unsigned char* base = (unsigned char*)cbp;
    *reinterpret_cast<short4v*>(base + fbase + (lg * 16 + lr) * 16 + half * 8) = hv;
    *reinterpret_cast<short4v*>(base + fbase + 1024 + (lg * 16 + lr) * 16 + half * 8) = lv;
}

// ---------------------------------------------------------------------------
// Kernel B: 3-product split-bf16 MFMA GEMM + top-2 -> bestk + rescue list.
// BM=64 rows x all 512 codes per block, grid 256, 8 waves (2/SIMD).
// amdgpu_waves_per_eu(2,2): tell the register allocator the TRUE occupancy
// (LDS caps us at 2 waves/SIMD) so the B-prefetch pipeline survives in regs
// (default heuristic squeezed to 116 VGPR and sank all prefetches -> 77us
// latency-bound plateau across r7/r8/r10).
// ---------------------------------------------------------------------------
__attribute__((amdgpu_waves_per_eu(2, 2)))
__global__ __launch_bounds__(512)
void vq_topk(const float* __restrict__ z,
             const unsigned short* __restrict__ cbp,
             int* __restrict__ bestk, int* __restrict__ rlist,
             int* __restrict__ rcnt) {
    __shared__ alignas(16) unsigned char LDS[2][BM * KP * 2 * 2];  // 2 x 64 KB

    const int tid = threadIdx.x;
    const int r0  = blockIdx.x * BM;
    const int l   = tid & 63;
    const int wv  = tid >> 6;        // 0..7
    const int lr  = l & 15;
    const int lg  = l >> 4;

    f32x4 acc[4][4];
#pragma unroll
    for (int m = 0; m < 4; ++m)
#pragma unroll
        for (int nt = 0; nt < 4; ++nt) acc[m][nt] = (f32x4){0.f, 0.f, 0.f, 0.f};

    const int aswz = (lr & 7) << 4;
    // lane-resolved base into packed B; fragment fi lives at byte fi*1024
    const unsigned char* bbase = (const unsigned char*)cbp + l * 16;
#define BFRAG(fi) (*reinterpret_cast<const short8*>(bbase + (unsigned)(fi) * 1024u))

    // staging decomposition: wave wv covers rows wv+8c (c=0..7) at f4-col l
    const int c4    = l;
    const int row0  = wv;
    const int swz_w = (row0 & 7) << 4;   // (row0+8c)&7 == row0&7
    const float* zbase = z + (size_t)(r0 + row0) * D + c4 * 4;

    // prologue: panel 0 -> buf 0
    {
        float4 zn[8];
#pragma unroll
        for (int c = 0; c < 8; ++c)
            zn[c] = *reinterpret_cast<const float4*>(zbase + (size_t)(8 * c) * D);
#pragma unroll
        for (int c = 0; c < 8; ++c) {
            const int ad = ((row0 + 8 * c) * 512 + c4 * 8) ^ swz_w;
            cvt_write(zn[c], &LDS[0][ad], &LDS[0][32768 + ad]);
        }
    }

#pragma unroll 1
    for (int p = 0; p < 4; ++p) {
        __syncthreads();                      // buf[p&1] staged; buf[(p+1)&1] free
        unsigned char* Ah  = &LDS[p & 1][0];
        unsigned char* Al  = Ah + 32768;
        unsigned char* Ahn = &LDS[(p + 1) & 1][0];

        // (a) issue next panel's global z loads early (T14)
        float4 zn[8];
        if (p < 3) {
#pragma unroll
            for (int c = 0; c < 8; ++c)
                zn[c] = *reinterpret_cast<const float4*>(
                    zbase + (size_t)(8 * c) * D + (p + 1) * KP);
        }

        // (b) MFMA: 8 k-steps of 32; B register pipeline one step ahead
        const int fp0 = (wv * 4 * 32 + p * 8) * 2;   // fragment index base
        short8 b0[4][2], b1[4][2];
#pragma unroll
        for (int nt = 0; nt < 4; ++nt) {
            const int fi = fp0 + nt * 64;            // (wv*4+nt)*32*2 = nt*64
            b0[nt][0] = BFRAG(fi + 0);
            b0[nt][1] = BFRAG(fi + 1);
        }
#pragma unroll 2
        for (int ks = 0; ks < 8; ++ks) {
            if (ks < 7) {
#pragma unroll
                for (int nt = 0; nt < 4; ++nt) {
                    const int fi = fp0 + nt * 64 + (ks + 1) * 2;
                    b1[nt][0] = BFRAG(fi + 0);
                    b1[nt][1] = BFRAG(fi + 1);
                }
            }
            short8 ah[4], al[4];
#pragma unroll
            for (int m = 0; m < 4; ++m) {
                const int ad = ((m * 16 + lr) * 512 + lg * 16 + ks * 64) ^ aswz;
                ah[m] = *reinterpret_cast<const short8*>(Ah + ad);
                al[m] = *reinterpret_cast<const short8*>(Al + ad);
            }
#pragma unroll
            for (int nt = 0; nt < 4; ++nt) {
                const short8 bh = b0[nt][0];
                const short8 bl = b0[nt][1];
#pragma unroll
                for (int m = 0; m < 4; ++m) {
                    acc[m][nt] = __builtin_amdgcn_mfma_f32_16x16x32_bf16(ah[m], bh, acc[m][nt], 0, 0, 0);
                    acc[m][nt] = __builtin_amdgcn_mfma_f32_16x16x32_bf16(ah[m], bl, acc[m][nt], 0, 0, 0);
                    acc[m][nt] = __builtin_amdgcn_mfma_f32_16x16x32_bf16(al[m], bh, acc[m][nt], 0, 0, 0);
                }
            }
            // rotate pipeline regs (renamed away by unroll-2)
#pragma unroll
            for (int nt = 0; nt < 4; ++nt) {
                b0[nt][0] = b1[nt][0];
                b0[nt][1] = b1[nt][1];
            }
        }

        // (c) convert + write next panel into the other buffer (VALU tail)
        if (p < 3) {
#pragma unroll
            for (int c = 0; c < 8; ++c) {
                const int ad = ((row0 + 8 * c) * 512 + c4 * 8) ^ swz_w;
                cvt_write(zn[c], Ahn + ad, Ahn + 32768 + ad);
            }
        }
    }
#undef BFRAG

    // ---- LDS no longer needed for A: alias reduction arrays ----
    __syncthreads();
    float* cv1 = (float*)&LDS[0][0];          // [8][BM]
    float* cv2 = (float*)&LDS[0][4096];       // [8][BM]
    int*   ci1 = (int*)  &LDS[0][8192];       // [8][BM]

    // ---- top-2 per row: nt scan, 16-lane butterfly, wave merge ----
    // acc[m][nt][r] = logits[row = m*16 + lg*4 + r][code = wv*64 + nt*16 + lr]
#pragma unroll
    for (int m = 0; m < 4; ++m)
#pragma unroll
        for (int r = 0; r < 4; ++r) {
            float v1 = acc[m][0][r];
            int   i1 = wv * 64 + lr;
            float v2 = -INFINITY;
#pragma unroll
            for (int nt = 1; nt < 4; ++nt) {
                const float v = acc[m][nt][r];
                const int   n = wv * 64 + nt * 16 + lr;
                if (v > v1) { v2 = v1; v1 = v; i1 = n; }
                else        { v2 = fmaxf(v2, v); }
            }
#pragma unroll
            for (int msk = 1; msk < 16; msk <<= 1) {
                const float ov1 = __shfl_xor(v1, msk);
                const float ov2 = __shfl_xor(v2, msk);
                const int   oi1 = __shfl_xor(i1, msk);
                if (ov1 > v1 || (ov1 == v1 && oi1 < i1)) { v2 = fmaxf(v1, ov2); v1 = ov1; i1 = oi1; }
                else                                     { v2 = fmaxf(v2, ov1); }
            }
            if (lr == 0) {
                const int row = m * 16 + lg * 4 + r;
                cv1[wv * BM + row] = v1; cv2[wv * BM + row] = v2; ci1[wv * BM + row] = i1;
            }
        }
    __syncthreads();
    if (tid < BM) {
        float v1 = cv1[tid], v2 = cv2[tid];
        int   i1 = ci1[tid];
        for (int w = 1; w < 8; ++w) {
            const float a1 = cv1[w * BM + tid], a2 = cv2[w * BM + tid];
            const int   b1 = ci1[w * BM + tid];
            if (a1 > v1 || (a1 == v1 && b1 < i1)) { v2 = fmaxf(v1, a2); v1 = a1; i1 = b1; }
            else                                  { v2 = fmaxf(v2, a1); }
        }
        bestk[r0 + tid] = i1;
        if (v1 - v2 < GAP_T) {
            const int pos = atomicAdd(rcnt, 1);
            rlist[pos] = r0 + tid;
        }
    }
}

// ---------------------------------------------------------------------------
// Kernel C: exact f32 rescue over the compacted row list; fixes bestk only.
// ---------------------------------------------------------------------------
__global__ __launch_bounds__(256)
void vq_rescue(const float* __restrict__ z, const float* __restrict__ cff,
               const int* __restrict__ rlist, const int* __restrict__ rcnt,
               int* __restrict__ bestk) {
    const int cnt = rcnt[0];
    const int tid = threadIdx.x;
    const int l   = tid & 63;
    const int wv  = tid >> 6;        // 0..3
    __shared__ float zs[D];
    __shared__ float wvv[4];
    __shared__ int   wvi[4];

    for (int i = blockIdx.x; i < cnt; i += gridDim.x) {
        const int row = rlist[i];
        __syncthreads();             // protect zs/wvv reuse across iterations
        reinterpret_cast<float4*>(zs)[tid] =
            reinterpret_cast<const float4*>(z + (size_t)row * D)[tid];
        __syncthreads();

        float v1 = -INFINITY;
        int   i1 = 0;
#pragma unroll 4
        for (int kk = 0; kk < 128; ++kk) {
            const int k = wv * 128 + kk;
            const float4* cr = reinterpret_cast<const float4*>(cff + (size_t)k * D);
            float s = 0.f;
#pragma unroll
            for (int j = 0; j < 4; ++j) {
                const float4 c = cr[j * 64 + l];           // coalesced 1KB/wave
                const float4 a = *reinterpret_cast<const float4*>(zs + j * 256 + l * 4);
                s = fmaf(c.x, a.x, s); s = fmaf(c.y, a.y, s);
                s = fmaf(c.z, a.z, s); s = fmaf(c.w, a.w, s);
            }
#pragma unroll
            for (int off = 32; off > 0; off >>= 1) s += __shfl_xor(s, off);
            if (s > v1) { v1 = s; i1 = k; }   // ascending k: first-index ties
        }
        if (l == 0) { wvv[wv] = v1; wvi[wv] = i1; }
        __syncthreads();
        if (tid == 0) {
            float bv = wvv[0]; int bi = wvi[0];
            for (int w = 1; w < 4; ++w)
                if (wvv[w] > bv || (wvv[w] == bv && wvi[w] < bi)) { bv = wvv[w]; bi = wvi[w]; }
            bestk[row] = bi;
        }
    }
}

// ---------------------------------------------------------------------------
// Kernel D: streaming epilogue. out = target * (1 + E[bestk[row]]).
// ---------------------------------------------------------------------------
__global__ __launch_bounds__(256)
void vq_epilogue(const float* __restrict__ tgt, const float* __restrict__ E,
                 const int* __restrict__ bestk, float* __restrict__ out) {
    const int tid = threadIdx.x;
    const int r0  = blockIdx.x * 8;
    int bi[8];
#pragma unroll
    for (int r = 0; r < 8; ++r) bi[r] = bestk[r0 + r];
#pragma unroll
    for (int r = 0; r < 8; ++r) {
        const float4 tv = reinterpret_cast<const float4*>(tgt + (size_t)(r0 + r) * D)[tid];
        const float4 ev = reinterpret_cast<const float4*>(E + (size_t)bi[r] * D)[tid];
        float4 o;
        o.x = tv.x * (1.0f + ev.x);
        o.y = tv.y * (1.0f + ev.y);
        o.z = tv.z * (1.0f + ev.z);
        o.w = tv.w * (1.0f + ev.w);
        reinterpret_cast<float4*>(out + (size_t)(r0 + r) * D)[tid] = o;
    }
}

extern "C" void kernel_launch(void* const* d_in, const int* in_sizes, int n_in,
                              void* d_out, int out_size, void* d_ws, size_t ws_size,
                              hipStream_t stream) {
    const float* z        = (const float*)d_in[0];
    const float* target   = (const float*)d_in[1];
    const float* codebook = (const float*)d_in[2];
    const float* E        = (const float*)d_in[3];
    float* out = (float*)d_out;

    unsigned short* cbp   = (unsigned short*)d_ws;              // 2 MB packed hi/lo
    float*          cff   = (float*)(cbp + (size_t)K * D * 2);  // 2 MB f32
    int*            bestk = (int*)(cff + (size_t)K * D);        // 64 KB
    int*            rlist = bestk + ROWS;                       // 64 KB
    int*            rcnt  = rlist + ROWS;                       // 4 B

    const int rows = in_sizes[0] / D;                           // 16384
    hipLaunchKernelGGL(prep_codebook, dim3(K), dim3(256), 0, stream,
                       codebook, cbp, cff, rcnt);
    hipLaunchKernelGGL(vq_topk, dim3(rows / BM), dim3(512), 0, stream,
                       z, cbp, bestk, rlist, rcnt);
    hipLaunchKernelGGL(vq_rescue, dim3(256), dim3(256), 0, stream,
                       z, cff, rlist, rcnt, bestk);
    hipLaunchKernelGGL(vq_epilogue, dim3(rows / 8), dim3(256), 0, stream,
                       target, E, bestk, out);
}

// Round 13
// 163.078 us; speedup vs baseline: 1.0066x; 1.0066x over previous
//
#include <hip/hip_runtime.h>
#include <math.h>

typedef short  short8  __attribute__((ext_vector_type(8)));
typedef short  short4v __attribute__((ext_vector_type(4)));
typedef float  f32x4   __attribute__((ext_vector_type(4)));

constexpr int D   = 1024;   // d_in = d_g
constexpr int K   = 512;    // codebook size
constexpr int BM  = 64;     // rows per block (vq_topk)
constexpr int KP  = 256;    // k-panel (f32 elements)
constexpr int ROWS = 16384;
constexpr float GAP_T = 2e-3f;   // ~25 sigma of 3-term split-bf16 noise

__device__ __forceinline__ unsigned short f2bf(float f) {
    unsigned u = __float_as_uint(f);
    u += 0x7FFFu + ((u >> 16) & 1u);          // round-to-nearest-even
    return (unsigned short)(u >> 16);
}
__device__ __forceinline__ float bf2f(unsigned short h) {
    return __uint_as_float(((unsigned)h) << 16);
}
// convert one float4 -> bf16 hi/lo 8B chunks and store to LDS
__device__ __forceinline__ void cvt_write(const float4 v,
                                          unsigned char* dh, unsigned char* dl) {
    const unsigned short h0 = f2bf(v.x), h1 = f2bf(v.y), h2 = f2bf(v.z), h3 = f2bf(v.w);
    const short4v hv = { (short)h0, (short)h1, (short)h2, (short)h3 };
    const short4v lv = { (short)f2bf(v.x - bf2f(h0)), (short)f2bf(v.y - bf2f(h1)),
                         (short)f2bf(v.z - bf2f(h2)), (short)f2bf(v.w - bf2f(h3)) };
    *reinterpret_cast<short4v*>(dh) = hv;
    *reinterpret_cast<short4v*>(dl) = lv;
}

// ---------------------------------------------------------------------------
// Kernel A: normalize codebook rows; emit MFMA-fragment-packed bf16 hi/lo
// (cbp) + f32 copy (cff, for rescue). Also zeroes the rescue counter.
// ---------------------------------------------------------------------------
__global__ __launch_bounds__(256)
void prep_codebook(const float* __restrict__ cb, unsigned short* __restrict__ cbp,
                   float* __restrict__ cff, int* __restrict__ rcnt) {
    if (blockIdx.x == 0 && threadIdx.x == 0) rcnt[0] = 0;
    const int n = blockIdx.x, tid = threadIdx.x;
    const float4 v = reinterpret_cast<const float4*>(cb + (size_t)n * D)[tid];
    float ss = v.x*v.x + v.y*v.y + v.z*v.z + v.w*v.w;
#pragma unroll
    for (int off = 32; off > 0; off >>= 1) ss += __shfl_down(ss, off);
    __shared__ float wss[4];
    if ((tid & 63) == 0) wss[tid >> 6] = ss;
    __syncthreads();
    const float tot   = wss[0] + wss[1] + wss[2] + wss[3];
    const float scale = 1.0f / fmaxf(sqrtf(tot), 1e-12f);
    float f[4] = { v.x*scale, v.y*scale, v.z*scale, v.w*scale };
    float4 fv = { f[0], f[1], f[2], f[3] };
    reinterpret_cast<float4*>(cff + (size_t)n * D)[tid] = fv;

    unsigned short h[4], lo[4];
#pragma unroll
    for (int i = 0; i < 4; ++i) { h[i] = f2bf(f[i]); lo[i] = f2bf(f[i] - bf2f(h[i])); }
    short4v hv = { (short)h[0], (short)h[1], (short)h[2], (short)h[3] };
    short4v lv = { (short)lo[0], (short)lo[1], (short)lo[2], (short)lo[3] };

    const int nt_g = n >> 4;           // code tile 0..31
    const int lr   = n & 15;
    const int ks_g = tid >> 3;         // k-step 0..31
    const int lg   = (tid >> 1) & 3;
    const int half = tid & 1;
    const size_t fbase = ((size_t)(nt_g * 32 + ks_g) * 2) * 1024;   // bytes
    unsigned char* base = (unsigned char*)cbp;
    *reinterpret_cast<short4v*>(base + fbase + (lg * 16 + lr) * 16 + half * 8) = hv;
    *reinterpret_cast<short4v*>(base + fbase + 1024 + (lg * 16 + lr) * 16 + half * 8) = lv;
}

// ---------------------------------------------------------------------------
// Kernel B: 3-product split-bf16 MFMA GEMM + top-2 -> bestk + rescue list.
// BM=64 rows x all 512 codes per block, grid 256, 8 waves (2/SIMD).
// amdgpu_waves_per_eu(2,2): tell the register allocator the TRUE occupancy
// (LDS caps us at 2 waves/SIMD) so the B-prefetch pipeline survives in regs
// (default heuristic squeezed to 116 VGPR and sank all prefetches -> 77us
// latency-bound plateau across r7/r8/r10).
// ---------------------------------------------------------------------------
__attribute__((amdgpu_waves_per_eu(2, 2)))
__global__ __launch_bounds__(512)
void vq_topk(const float* __restrict__ z,
             const unsigned short* __restrict__ cbp,
             int* __restrict__ bestk, int* __restrict__ rlist,
             int* __restrict__ rcnt) {
    __shared__ alignas(16) unsigned char LDS[2][BM * KP * 2 * 2];  // 2 x 64 KB

    const int tid = threadIdx.x;
    const int r0  = blockIdx.x * BM;
    const int l   = tid & 63;
    const int wv  = tid >> 6;        // 0..7
    const int lr  = l & 15;
    const int lg  = l >> 4;

    f32x4 acc[4][4];
#pragma unroll
    for (int m = 0; m < 4; ++m)
#pragma unroll
        for (int nt = 0; nt < 4; ++nt) acc[m][nt] = (f32x4){0.f, 0.f, 0.f, 0.f};

    const int aswz = (lr & 7) << 4;
    // lane-resolved base into packed B; fragment fi lives at byte fi*1024
    const unsigned char* bbase = (const unsigned char*)cbp + l * 16;
#define BFRAG(fi) (*reinterpret_cast<const short8*>(bbase + (unsigned)(fi) * 1024u))

    // staging decomposition: wave wv covers rows wv+8c (c=0..7) at f4-col l
    const int c4    = l;
    const int row0  = wv;
    const int swz_w = (row0 & 7) << 4;   // (row0+8c)&7 == row0&7
    const float* zbase = z + (size_t)(r0 + row0) * D + c4 * 4;

    // prologue: panel 0 -> buf 0
    {
        float4 zn[8];
#pragma unroll
        for (int c = 0; c < 8; ++c)
            zn[c] = *reinterpret_cast<const float4*>(zbase + (size_t)(8 * c) * D);
#pragma unroll
        for (int c = 0; c < 8; ++c) {
            const int ad = ((row0 + 8 * c) * 512 + c4 * 8) ^ swz_w;
            cvt_write(zn[c], &LDS[0][ad], &LDS[0][32768 + ad]);
        }
    }

#pragma unroll 1
    for (int p = 0; p < 4; ++p) {
        __syncthreads();                      // buf[p&1] staged; buf[(p+1)&1] free
        unsigned char* Ah  = &LDS[p & 1][0];
        unsigned char* Al  = Ah + 32768;
        unsigned char* Ahn = &LDS[(p + 1) & 1][0];

        // (a) issue next panel's global z loads early (T14)
        float4 zn[8];
        if (p < 3) {
#pragma unroll
            for (int c = 0; c < 8; ++c)
                zn[c] = *reinterpret_cast<const float4*>(
                    zbase + (size_t)(8 * c) * D + (p + 1) * KP);
        }

        // (b) MFMA: 8 k-steps of 32; B register pipeline one step ahead
        const int fp0 = (wv * 4 * 32 + p * 8) * 2;   // fragment index base
        short8 b0[4][2], b1[4][2];
#pragma unroll
        for (int nt = 0; nt < 4; ++nt) {
            const int fi = fp0 + nt * 64;            // (wv*4+nt)*32*2 = nt*64
            b0[nt][0] = BFRAG(fi + 0);
            b0[nt][1] = BFRAG(fi + 1);
        }
#pragma unroll 2
        for (int ks = 0; ks < 8; ++ks) {
            if (ks < 7) {
#pragma unroll
                for (int nt = 0; nt < 4; ++nt) {
                    const int fi = fp0 + nt * 64 + (ks + 1) * 2;
                    b1[nt][0] = BFRAG(fi + 0);
                    b1[nt][1] = BFRAG(fi + 1);
                }
            }
            short8 ah[4], al[4];
#pragma unroll
            for (int m = 0; m < 4; ++m) {
                const int ad = ((m * 16 + lr) * 512 + lg * 16 + ks * 64) ^ aswz;
                ah[m] = *reinterpret_cast<const short8*>(Ah + ad);
                al[m] = *reinterpret_cast<const short8*>(Al + ad);
            }
#pragma unroll
            for (int nt = 0; nt < 4; ++nt) {
                const short8 bh = b0[nt][0];
                const short8 bl = b0[nt][1];
#pragma unroll
                for (int m = 0; m < 4; ++m) {
                    acc[m][nt] = __builtin_amdgcn_mfma_f32_16x16x32_bf16(ah[m], bh, acc[m][nt], 0, 0, 0);
                    acc[m][nt] = __builtin_amdgcn_mfma_f32_16x16x32_bf16(ah[m], bl, acc[m][nt], 0, 0, 0);
                    acc[m][nt] = __builtin_amdgcn_mfma_f32_16x16x32_bf16(al[m], bh, acc[m][nt], 0, 0, 0);
                }
            }
            // rotate pipeline regs (renamed away by unroll-2)
#pragma unroll
            for (int nt = 0; nt < 4; ++nt) {
                b0[nt][0] = b1[nt][0];
                b0[nt][1] = b1[nt][1];
            }
        }

        // (c) convert + write next panel into the other buffer (VALU tail)
        if (p < 3) {
#pragma unroll
            for (int c = 0; c < 8; ++c) {
                const int ad = ((row0 + 8 * c) * 512 + c4 * 8) ^ swz_w;
                cvt_write(zn[c], Ahn + ad, Ahn + 32768 + ad);
            }
        }
    }
#undef BFRAG

    // ---- LDS no longer needed for A: alias reduction arrays ----
    __syncthreads();
    float* cv1 = (float*)&LDS[0][0];          // [8][BM]
    float* cv2 = (float*)&LDS[0][4096];       // [8][BM]
    int*   ci1 = (int*)  &LDS[0][8192];       // [8][BM]

    // ---- top-2 per row: nt scan, 16-lane butterfly, wave merge ----
    // acc[m][nt][r] = logits[row = m*16 + lg*4 + r][code = wv*64 + nt*16 + lr]
#pragma unroll
    for (int m = 0; m < 4; ++m)
#pragma unroll
        for (int r = 0; r < 4; ++r) {
            float v1 = acc[m][0][r];
            int   i1 = wv * 64 + lr;
            float v2 = -INFINITY;
#pragma unroll
            for (int nt = 1; nt < 4; ++nt) {
                const float v = acc[m][nt][r];
                const int   n = wv * 64 + nt * 16 + lr;
                if (v > v1) { v2 = v1; v1 = v; i1 = n; }
                else        { v2 = fmaxf(v2, v); }
            }
#pragma unroll
            for (int msk = 1; msk < 16; msk <<= 1) {
                const float ov1 = __shfl_xor(v1, msk);
                const float ov2 = __shfl_xor(v2, msk);
                const int   oi1 = __shfl_xor(i1, msk);
                if (ov1 > v1 || (ov1 == v1 && oi1 < i1)) { v2 = fmaxf(v1, ov2); v1 = ov1; i1 = oi1; }
                else                                     { v2 = fmaxf(v2, ov1); }
            }
            if (lr == 0) {
                const int row = m * 16 + lg * 4 + r;
                cv1[wv * BM + row] = v1; cv2[wv * BM + row] = v2; ci1[wv * BM + row] = i1;
            }
        }
    __syncthreads();
    if (tid < BM) {
        float v1 = cv1[tid], v2 = cv2[tid];
        int   i1 = ci1[tid];
        for (int w = 1; w < 8; ++w) {
            const float a1 = cv1[w * BM + tid], a2 = cv2[w * BM + tid];
            const int   b1 = ci1[w * BM + tid];
            if (a1 > v1 || (a1 == v1 && b1 < i1)) { v2 = fmaxf(v1, a2); v1 = a1; i1 = b1; }
            else                                  { v2 = fmaxf(v2, a1); }
        }
        bestk[r0 + tid] = i1;
        if (v1 - v2 < GAP_T) {
            const int pos = atomicAdd(rcnt, 1);
            rlist[pos] = r0 + tid;
        }
    }
}

// ---------------------------------------------------------------------------
// Kernel C: exact f32 rescue over the compacted row list; fixes bestk only.
// ---------------------------------------------------------------------------
__global__ __launch_bounds__(256)
void vq_rescue(const float* __restrict__ z, const float* __restrict__ cff,
               const int* __restrict__ rlist, const int* __restrict__ rcnt,
               int* __restrict__ bestk) {
    const int cnt = rcnt[0];
    const int tid = threadIdx.x;
    const int l   = tid & 63;
    const int wv  = tid >> 6;        // 0..3
    __shared__ float zs[D];
    __shared__ float wvv[4];
    __shared__ int   wvi[4];

    for (int i = blockIdx.x; i < cnt; i += gridDim.x) {
        const int row = rlist[i];
        __syncthreads();             // protect zs/wvv reuse across iterations
        reinterpret_cast<float4*>(zs)[tid] =
            reinterpret_cast<const float4*>(z + (size_t)row * D)[tid];
        __syncthreads();

        float v1 = -INFINITY;
        int   i1 = 0;
#pragma unroll 4
        for (int kk = 0; kk < 128; ++kk) {
            const int k = wv * 128 + kk;
            const float4* cr = reinterpret_cast<const float4*>(cff + (size_t)k * D);
            float s = 0.f;
#pragma unroll
            for (int j = 0; j < 4; ++j) {
                const float4 c = cr[j * 64 + l];           // coalesced 1KB/wave
                const float4 a = *reinterpret_cast<const float4*>(zs + j * 256 + l * 4);
                s = fmaf(c.x, a.x, s); s = fmaf(c.y, a.y, s);
                s = fmaf(c.z, a.z, s); s = fmaf(c.w, a.w, s);
            }
#pragma unroll
            for (int off = 32; off > 0; off >>= 1) s += __shfl_xor(s, off);
            if (s > v1) { v1 = s; i1 = k; }   // ascending k: first-index ties
        }
        if (l == 0) { wvv[wv] = v1; wvi[wv] = i1; }
        __syncthreads();
        if (tid == 0) {
            float bv = wvv[0]; int bi = wvi[0];
            for (int w = 1; w < 4; ++w)
                if (wvv[w] > bv || (wvv[w] == bv && wvi[w] < bi)) { bv = wvv[w]; bi = wvi[w]; }
            bestk[row] = bi;
        }
    }
}

// ---------------------------------------------------------------------------
// Kernel D: streaming epilogue. out = target * (1 + E[bestk[row]]).
// ---------------------------------------------------------------------------
__global__ __launch_bounds__(256)
void vq_epilogue(const float* __restrict__ tgt, const float* __restrict__ E,
                 const int* __restrict__ bestk, float* __restrict__ out) {
    const int tid = threadIdx.x;
    const int r0  = blockIdx.x * 8;
    int bi[8];
#pragma unroll
    for (int r = 0; r < 8; ++r) bi[r] = bestk[r0 + r];
#pragma unroll
    for (int r = 0; r < 8; ++r) {
        const float4 tv = reinterpret_cast<const float4*>(tgt + (size_t)(r0 + r) * D)[tid];
        const float4 ev = reinterpret_cast<const float4*>(E + (size_t)bi[r] * D)[tid];
        float4 o;
        o.x = tv.x * (1.0f + ev.x);
        o.y = tv.y * (1.0f + ev.y);
        o.z = tv.z * (1.0f + ev.z);
        o.w = tv.w * (1.0f + ev.w);
        reinterpret_cast<float4*>(out + (size_t)(r0 + r) * D)[tid] = o;
    }
}

extern "C" void kernel_launch(void* const* d_in, const int* in_sizes, int n_in,
                              void* d_out, int out_size, void* d_ws, size_t ws_size,
                              hipStream_t stream) {
    const float* z        = (const float*)d_in[0];
    const float* target   = (const float*)d_in[1];
    const float* codebook = (const float*)d_in[2];
    const float* E        = (const float*)d_in[3];
    float* out = (float*)d_out;

    unsigned short* cbp   = (unsigned short*)d_ws;              // 2 MB packed hi/lo
    float*          cff   = (float*)(cbp + (size_t)K * D * 2);  // 2 MB f32
    int*            bestk = (int*)(cff + (size_t)K * D);        // 64 KB
    int*            rlist = bestk + ROWS;                       // 64 KB
    int*            rcnt  = rlist + ROWS;                       // 4 B

    const int rows = in_sizes[0] / D;                           // 16384
    hipLaunchKernelGGL(prep_codebook, dim3(K), dim3(256), 0, stream,
                       codebook, cbp, cff, rcnt);
    hipLaunchKernelGGL(vq_topk, dim3(rows / BM), dim3(512), 0, stream,
                       z, cbp, bestk, rlist, rcnt);
    hipLaunchKernelGGL(vq_rescue, dim3(256), dim3(256), 0, stream,
                       z, cff, rlist, rcnt, bestk);
    hipLaunchKernelGGL(vq_epilogue, dim3(rows / 8), dim3(256), 0, stream,
                       target, E, bestk, out);
}

// Round 14
// 125.136 us; speedup vs baseline: 1.3118x; 1.3032x over previous
//
#include <hip/hip_runtime.h>
#include <math.h>

typedef short  short8  __attribute__((ext_vector_type(8)));
typedef short  short4v __attribute__((ext_vector_type(4)));
typedef float  f32x4   __attribute__((ext_vector_type(4)));

constexpr int D   = 1024;   // d_in = d_g
constexpr int K   = 512;    // codebook size
constexpr int BM  = 64;     // rows per block (vq_topk)
constexpr int KP  = 256;    // k-panel (f32 elements)
constexpr int ROWS = 16384;
constexpr float GAP_T = 2e-3f;   // ~400 sigma of 3-term split-bf16 noise

__device__ __forceinline__ unsigned short f2bf(float f) {
    unsigned u = __float_as_uint(f);
    u += 0x7FFFu + ((u >> 16) & 1u);          // round-to-nearest-even
    return (unsigned short)(u >> 16);
}
__device__ __forceinline__ float bf2f(unsigned short h) {
    return __uint_as_float(((unsigned)h) << 16);
}
// convert one float4 -> bf16 hi/lo 8B chunks and store to LDS
__device__ __forceinline__ void cvt_write(const float4 v,
                                          unsigned char* dh, unsigned char* dl) {
    const unsigned short h0 = f2bf(v.x), h1 = f2bf(v.y), h2 = f2bf(v.z), h3 = f2bf(v.w);
    const short4v hv = { (short)h0, (short)h1, (short)h2, (short)h3 };
    const short4v lv = { (short)f2bf(v.x - bf2f(h0)), (short)f2bf(v.y - bf2f(h1)),
                         (short)f2bf(v.z - bf2f(h2)), (short)f2bf(v.w - bf2f(h3)) };
    *reinterpret_cast<short4v*>(dh) = hv;
    *reinterpret_cast<short4v*>(dl) = lv;
}

// ---------------------------------------------------------------------------
// Kernel A: normalize codebook rows; emit MFMA-fragment-packed bf16 hi/lo
// (cbp) + TRANSPOSED f32 copy cft[d][k] (for the rescue scan). Zeroes rcnt.
// ---------------------------------------------------------------------------
__global__ __launch_bounds__(256)
void prep_codebook(const float* __restrict__ cb, unsigned short* __restrict__ cbp,
                   float* __restrict__ cft, int* __restrict__ rcnt) {
    if (blockIdx.x == 0 && threadIdx.x == 0) rcnt[0] = 0;
    const int n = blockIdx.x, tid = threadIdx.x;
    const float4 v = reinterpret_cast<const float4*>(cb + (size_t)n * D)[tid];
    float ss = v.x*v.x + v.y*v.y + v.z*v.z + v.w*v.w;
#pragma unroll
    for (int off = 32; off > 0; off >>= 1) ss += __shfl_down(ss, off);
    __shared__ float wss[4];
    if ((tid & 63) == 0) wss[tid >> 6] = ss;
    __syncthreads();
    const float tot   = wss[0] + wss[1] + wss[2] + wss[3];
    const float scale = 1.0f / fmaxf(sqrtf(tot), 1e-12f);
    float f[4] = { v.x*scale, v.y*scale, v.z*scale, v.w*scale };
    const int d0 = tid * 4;
#pragma unroll
    for (int i = 0; i < 4; ++i) cft[(size_t)(d0 + i) * K + n] = f[i];

    unsigned short h[4], lo[4];
#pragma unroll
    for (int i = 0; i < 4; ++i) { h[i] = f2bf(f[i]); lo[i] = f2bf(f[i] - bf2f(h[i])); }
    short4v hv = { (short)h[0], (short)h[1], (short)h[2], (short)h[3] };
    short4v lv = { (short)lo[0], (short)lo[1], (short)lo[2], (short)lo[3] };

    const int nt_g = n >> 4;           // code tile 0..31
    const int lr   = n & 15;
    const int ks_g = tid >> 3;         // k-step 0..31
    const int lg   = (tid >> 1) & 3;
    const int half = tid & 1;
    const size_t fbase = ((size_t)(nt_g * 32 + ks_g) * 2) * 1024;   // bytes
    unsigned char* base = (unsigned char*)cbp;
    *reinterpret_cast<short4v*>(base + fbase + (lg * 16 + lr) * 16 + half * 8) = hv;
    *reinterpret_cast<short4v*>(base + fbase + 1024 + (lg * 16 + lr) * 16 + half * 8) = lv;
}

// ---------------------------------------------------------------------------
// Kernel B: 3-product split-bf16 MFMA GEMM + top-2 -> bestk + rescue list.
// BM=64 rows x all 512 codes per block, grid 256, 8 waves (2/SIMD).
// amdgpu_waves_per_eu(2,2): true-occupancy register budget so the B-prefetch
// pipeline survives in regs (default squeezed to 116 VGPR -> 77us plateau).
// ---------------------------------------------------------------------------
__attribute__((amdgpu_waves_per_eu(2, 2)))
__global__ __launch_bounds__(512)
void vq_topk(const float* __restrict__ z,
             const unsigned short* __restrict__ cbp,
             int* __restrict__ bestk, int* __restrict__ rlist,
             int* __restrict__ rcnt) {
    __shared__ alignas(16) unsigned char LDS[2][BM * KP * 2 * 2];  // 2 x 64 KB

    const int tid = threadIdx.x;
    const int r0  = blockIdx.x * BM;
    const int l   = tid & 63;
    const int wv  = tid >> 6;        // 0..7
    const int lr  = l & 15;
    const int lg  = l >> 4;

    f32x4 acc[4][4];
#pragma unroll
    for (int m = 0; m < 4; ++m)
#pragma unroll
        for (int nt = 0; nt < 4; ++nt) acc[m][nt] = (f32x4){0.f, 0.f, 0.f, 0.f};

    const int aswz = (lr & 7) << 4;
    // lane-resolved base into packed B; fragment fi lives at byte fi*1024
    const unsigned char* bbase = (const unsigned char*)cbp + l * 16;
#define BFRAG(fi) (*reinterpret_cast<const short8*>(bbase + (unsigned)(fi) * 1024u))

    // staging decomposition: wave wv covers rows wv+8c (c=0..7) at f4-col l
    const int c4    = l;
    const int row0  = wv;
    const int swz_w = (row0 & 7) << 4;   // (row0+8c)&7 == row0&7
    const float* zbase = z + (size_t)(r0 + row0) * D + c4 * 4;

    // prologue: panel 0 -> buf 0
    {
        float4 zn[8];
#pragma unroll
        for (int c = 0; c < 8; ++c)
            zn[c] = *reinterpret_cast<const float4*>(zbase + (size_t)(8 * c) * D);
#pragma unroll
        for (int c = 0; c < 8; ++c) {
            const int ad = ((row0 + 8 * c) * 512 + c4 * 8) ^ swz_w;
            cvt_write(zn[c], &LDS[0][ad], &LDS[0][32768 + ad]);
        }
    }

#pragma unroll 1
    for (int p = 0; p < 4; ++p) {
        __syncthreads();                      // buf[p&1] staged; buf[(p+1)&1] free
        unsigned char* Ah  = &LDS[p & 1][0];
        unsigned char* Al  = Ah + 32768;
        unsigned char* Ahn = &LDS[(p + 1) & 1][0];

        // (a) issue next panel's global z loads early (T14)
        float4 zn[8];
        if (p < 3) {
#pragma unroll
            for (int c = 0; c < 8; ++c)
                zn[c] = *reinterpret_cast<const float4*>(
                    zbase + (size_t)(8 * c) * D + (p + 1) * KP);
        }

        // (b) MFMA: 8 k-steps of 32; B register pipeline one step ahead
        const int fp0 = (wv * 4 * 32 + p * 8) * 2;   // fragment index base
        short8 b0[4][2], b1[4][2];
#pragma unroll
        for (int nt = 0; nt < 4; ++nt) {
            const int fi = fp0 + nt * 64;            // (wv*4+nt)*32*2 = nt*64
            b0[nt][0] = BFRAG(fi + 0);
            b0[nt][1] = BFRAG(fi + 1);
        }
#pragma unroll 2
        for (int ks = 0; ks < 8; ++ks) {
            if (ks < 7) {
#pragma unroll
                for (int nt = 0; nt < 4; ++nt) {
                    const int fi = fp0 + nt * 64 + (ks + 1) * 2;
                    b1[nt][0] = BFRAG(fi + 0);
                    b1[nt][1] = BFRAG(fi + 1);
                }
            }
            short8 ah[4], al[4];
#pragma unroll
            for (int m = 0; m < 4; ++m) {
                const int ad = ((m * 16 + lr) * 512 + lg * 16 + ks * 64) ^ aswz;
                ah[m] = *reinterpret_cast<const short8*>(Ah + ad);
                al[m] = *reinterpret_cast<const short8*>(Al + ad);
            }
#pragma unroll
            for (int nt = 0; nt < 4; ++nt) {
                const short8 bh = b0[nt][0];
                const short8 bl = b0[nt][1];
#pragma unroll
                for (int m = 0; m < 4; ++m) {
                    acc[m][nt] = __builtin_amdgcn_mfma_f32_16x16x32_bf16(ah[m], bh, acc[m][nt], 0, 0, 0);
                    acc[m][nt] = __builtin_amdgcn_mfma_f32_16x16x32_bf16(ah[m], bl, acc[m][nt], 0, 0, 0);
                    acc[m][nt] = __builtin_amdgcn_mfma_f32_16x16x32_bf16(al[m], bh, acc[m][nt], 0, 0, 0);
                }
            }
            // rotate pipeline regs (renamed away by unroll-2)
#pragma unroll
            for (int nt = 0; nt < 4; ++nt) {
                b0[nt][0] = b1[nt][0];
                b0[nt][1] = b1[nt][1];
            }
        }

        // (c) convert + write next panel into the other buffer (VALU tail)
        if (p < 3) {
#pragma unroll
            for (int c = 0; c < 8; ++c) {
                const int ad = ((row0 + 8 * c) * 512 + c4 * 8) ^ swz_w;
                cvt_write(zn[c], Ahn + ad, Ahn + 32768 + ad);
            }
        }
    }
#undef BFRAG

    // ---- LDS no longer needed for A: alias reduction arrays ----
    __syncthreads();
    float* cv1 = (float*)&LDS[0][0];          // [8][BM]
    float* cv2 = (float*)&LDS[0][4096];       // [8][BM]
    int*   ci1 = (int*)  &LDS[0][8192];       // [8][BM]

    // ---- top-2 per row: nt scan, 16-lane butterfly, wave merge ----
    // acc[m][nt][r] = logits[row = m*16 + lg*4 + r][code = wv*64 + nt*16 + lr]
#pragma unroll
    for (int m = 0; m < 4; ++m)
#pragma unroll
        for (int r = 0; r < 4; ++r) {
            float v1 = acc[m][0][r];
            int   i1 = wv * 64 + lr;
            float v2 = -INFINITY;
#pragma unroll
            for (int nt = 1; nt < 4; ++nt) {
                const float v = acc[m][nt][r];
                const int   n = wv * 64 + nt * 16 + lr;
                if (v > v1) { v2 = v1; v1 = v; i1 = n; }
                else        { v2 = fmaxf(v2, v); }
            }
#pragma unroll
            for (int msk = 1; msk < 16; msk <<= 1) {
                const float ov1 = __shfl_xor(v1, msk);
                const float ov2 = __shfl_xor(v2, msk);
                const int   oi1 = __shfl_xor(i1, msk);
                if (ov1 > v1 || (ov1 == v1 && oi1 < i1)) { v2 = fmaxf(v1, ov2); v1 = ov1; i1 = oi1; }
                else                                     { v2 = fmaxf(v2, ov1); }
            }
            if (lr == 0) {
                const int row = m * 16 + lg * 4 + r;
                cv1[wv * BM + row] = v1; cv2[wv * BM + row] = v2; ci1[wv * BM + row] = i1;
            }
        }
    __syncthreads();
    if (tid < BM) {
        float v1 = cv1[tid], v2 = cv2[tid];
        int   i1 = ci1[tid];
        for (int w = 1; w < 8; ++w) {
            const float a1 = cv1[w * BM + tid], a2 = cv2[w * BM + tid];
            const int   b1 = ci1[w * BM + tid];
            if (a1 > v1 || (a1 == v1 && b1 < i1)) { v2 = fmaxf(v1, a2); v1 = a1; i1 = b1; }
            else                                  { v2 = fmaxf(v2, a1); }
        }
        bestk[r0 + tid] = i1;
        if (v1 - v2 < GAP_T) {
            const int pos = atomicAdd(rcnt, 1);
            rlist[pos] = r0 + tid;
        }
    }
}

// ---------------------------------------------------------------------------
// Kernel C: exact f32 rescue over the compacted row list; fixes bestk only.
// Transposed-codebook scan: thread t owns codes {2t, 2t+1}; per d one
// coalesced float2 load + 2 fma. No per-iteration cross-lane ops.
// ---------------------------------------------------------------------------
__global__ __launch_bounds__(256)
void vq_rescue(const float* __restrict__ z, const float* __restrict__ cft,
               const int* __restrict__ rlist, const int* __restrict__ rcnt,
               int* __restrict__ bestk) {
    const int cnt = rcnt[0];
    const int tid = threadIdx.x;
    const int l   = tid & 63;
    const int wv  = tid >> 6;        // 0..3
    __shared__ float zs[D];
    __shared__ float wvv[4];
    __shared__ int   wvi[4];

    const float2* ct = reinterpret_cast<const float2*>(cft) + tid;  // [d][256 x float2]

    for (int i = blockIdx.x; i < cnt; i += gridDim.x) {
        const int row = rlist[i];
        __syncthreads();             // protect zs/wvv reuse across iterations
        reinterpret_cast<float4*>(zs)[tid] =
            reinterpret_cast<const float4*>(z + (size_t)row * D)[tid];
        __syncthreads();

        float s0 = 0.f, s1 = 0.f, t0 = 0.f, t1 = 0.f;
#pragma unroll 8
        for (int d = 0; d < D; d += 2) {
            const float2 va = ct[(size_t)d * 256];
            const float2 vb = ct[(size_t)(d + 1) * 256];
            const float  a  = zs[d];
            const float  b  = zs[d + 1];
            s0 = fmaf(a, va.x, s0); s1 = fmaf(a, va.y, s1);
            t0 = fmaf(b, vb.x, t0); t1 = fmaf(b, vb.y, t1);
        }
        s0 += t0; s1 += t1;

        float bv; int bi;
        if (s1 > s0) { bv = s1; bi = tid * 2 + 1; }
        else         { bv = s0; bi = tid * 2; }      // tie -> lower index
#pragma unroll
        for (int off = 32; off > 0; off >>= 1) {
            const float ov = __shfl_down(bv, off);
            const int   oi = __shfl_down(bi, off);
            if (ov > bv || (ov == bv && oi < bi)) { bv = ov; bi = oi; }
        }
        if (l == 0) { wvv[wv] = bv; wvi[wv] = bi; }
        __syncthreads();
        if (tid == 0) {
            float fv = wvv[0]; int fi = wvi[0];
            for (int w = 1; w < 4; ++w)
                if (wvv[w] > fv || (wvv[w] == fv && wvi[w] < fi)) { fv = wvv[w]; fi = wvi[w]; }
            bestk[row] = fi;
        }
    }
}

// ---------------------------------------------------------------------------
// Kernel D: streaming epilogue. out = target * (1 + E[bestk[row]]).
// ---------------------------------------------------------------------------
__global__ __launch_bounds__(256)
void vq_epilogue(const float* __restrict__ tgt, const float* __restrict__ E,
                 const int* __restrict__ bestk, float* __restrict__ out) {
    const int tid = threadIdx.x;
    const int r0  = blockIdx.x * 8;
    int bi[8];
#pragma unroll
    for (int r = 0; r < 8; ++r) bi[r] = bestk[r0 + r];
#pragma unroll
    for (int r = 0; r < 8; ++r) {
        const float4 tv = reinterpret_cast<const float4*>(tgt + (size_t)(r0 + r) * D)[tid];
        const float4 ev = reinterpret_cast<const float4*>(E + (size_t)bi[r] * D)[tid];
        float4 o;
        o.x = tv.x * (1.0f + ev.x);
        o.y = tv.y * (1.0f + ev.y);
        o.z = tv.z * (1.0f + ev.z);
        o.w = tv.w * (1.0f + ev.w);
        reinterpret_cast<float4*>(out + (size_t)(r0 + r) * D)[tid] = o;
    }
}

extern "C" void kernel_launch(void* const* d_in, const int* in_sizes, int n_in,
                              void* d_out, int out_size, void* d_ws, size_t ws_size,
                              hipStream_t stream) {
    const float* z        = (const float*)d_in[0];
    const float* target   = (const float*)d_in[1];
    const float* codebook = (const float*)d_in[2];
    const float* E        = (const float*)d_in[3];
    float* out = (float*)d_out;

    unsigned short* cbp   = (unsigned short*)d_ws;              // 2 MB packed hi/lo
    float*          cft   = (float*)(cbp + (size_t)K * D * 2);  // 2 MB f32 transposed
    int*            bestk = (int*)(cft + (size_t)K * D);        // 64 KB
    int*            rlist = bestk + ROWS;                       // 64 KB
    int*            rcnt  = rlist + ROWS;                       // 4 B

    const int rows = in_sizes[0] / D;                           // 16384
    hipLaunchKernelGGL(prep_codebook, dim3(K), dim3(256), 0, stream,
                       codebook, cbp, cft, rcnt);
    hipLaunchKernelGGL(vq_topk, dim3(rows / BM), dim3(512), 0, stream,
                       z, cbp, bestk, rlist, rcnt);
    hipLaunchKernelGGL(vq_rescue, dim3(256), dim3(256), 0, stream,
                       z, cft, rlist, rcnt, bestk);
    hipLaunchKernelGGL(vq_epilogue, dim3(rows / 8), dim3(256), 0, stream,
                       target, E, bestk, out);
}